// Round 3
// baseline (281.193 us; speedup 1.0000x reference)
//
#include <hip/hip_runtime.h>

// Gabor layer: out[i,o] = sin(x[i]·W[o] + b[o]) * exp(-0.5*||x[i]-mu[o]||^2 * gamma[o])
// B=262144 rows, O=256 outputs, D=2.  Pure HBM-write-bound: 256 MiB out.
// Floor ~41 us at the 6.6 TB/s the harness fill kernel demonstrates.

#define NROWS 262144
#define NOUT  256
#define ROWS_PER_BLOCK 64

// Native clang vector type: __builtin_nontemporal_store requires a vector of
// float, not HIP's struct-based float4.
typedef float vfloat4 __attribute__((ext_vector_type(4)));

__global__ void gabor_kernel(const float* __restrict__ x,
                             const float* __restrict__ W,
                             const float* __restrict__ b,
                             const float* __restrict__ mu,
                             const float* __restrict__ gamma,
                             float* __restrict__ out)
{
    const int tid  = threadIdx.x;
    const int oq   = (tid & 63) * 4;   // this thread's 4 consecutive outputs
    const int rsub = tid >> 6;         // row offset 0..3 within a chunk

    // Per-output constants: 6 vector loads (W/mu rows for oq..oq+3 are 8
    // consecutive floats each; b/gamma 4 consecutive). All L1-resident.
    const float4 w01 = *reinterpret_cast<const float4*>(W  + oq * 2);
    const float4 w23 = *reinterpret_cast<const float4*>(W  + oq * 2 + 4);
    const float4 m01 = *reinterpret_cast<const float4*>(mu + oq * 2);
    const float4 m23 = *reinterpret_cast<const float4*>(mu + oq * 2 + 4);
    const float4 bb4 = *reinterpret_cast<const float4*>(b  + oq);
    const float4 g4  = *reinterpret_cast<const float4*>(gamma + oq);

    const float W0[4] = {w01.x, w01.z, w23.x, w23.z};
    const float W1[4] = {w01.y, w01.w, w23.y, w23.w};
    const float M0[4] = {m01.x, m01.z, m23.x, m23.z};
    const float M1[4] = {m01.y, m01.w, m23.y, m23.w};
    const float BB[4] = {bb4.x, bb4.y, bb4.z, bb4.w};
    const float NG[4] = {-0.5f * g4.x, -0.5f * g4.y, -0.5f * g4.z, -0.5f * g4.w};

    const int row_base = blockIdx.x * ROWS_PER_BLOCK;

    // 16 iterations; unroll 4 => 4 independent x-loads and 4 stores in
    // flight per wave (MLP), instead of a serialized load->compute->store chain.
#pragma unroll 4
    for (int r = rsub; r < ROWS_PER_BLOCK; r += 4) {
        const int i = row_base + r;
        const float2 xv = *reinterpret_cast<const float2*>(x + (size_t)i * 2);

        float res[4];
#pragma unroll
        for (int j = 0; j < 4; ++j) {
            const float lin = __fmaf_rn(xv.x, W0[j], __fmaf_rn(xv.y, W1[j], BB[j]));
            const float dx  = xv.x - M0[j];
            const float dy  = xv.y - M1[j];
            const float d2  = __fmaf_rn(dy, dy, dx * dx);
            res[j] = __sinf(lin) * __expf(d2 * NG[j]);
        }
        vfloat4 v = {res[0], res[1], res[2], res[3]};
        // Wave writes 64 contiguous float4 = 1 KiB per row; nt streams past L2.
        __builtin_nontemporal_store(
            v, reinterpret_cast<vfloat4*>(out + (size_t)i * NOUT + oq));
    }
}

extern "C" void kernel_launch(void* const* d_in, const int* in_sizes, int n_in,
                              void* d_out, int out_size, void* d_ws, size_t ws_size,
                              hipStream_t stream)
{
    const float* x     = (const float*)d_in[0];  // (B, 2)
    const float* W     = (const float*)d_in[1];  // (O, 2)
    const float* b     = (const float*)d_in[2];  // (O,)
    const float* mu    = (const float*)d_in[3];  // (1, O, 2)
    const float* gamma = (const float*)d_in[4];  // (O,)
    float* out = (float*)d_out;                  // (B, O)

    const int grid = NROWS / ROWS_PER_BLOCK;     // 4096 blocks, 256 thr each
    gabor_kernel<<<grid, 256, 0, stream>>>(x, W, b, mu, gamma, out);
}